// Round 11
// baseline (224.687 us; speedup 1.0000x reference)
//
#include <hip/hip_runtime.h>

#define HDIM 128
#define BN_EPS 1e-5f
#define SCAN_BINS 1024
#define NPART 8    // XCD count: target-range partitions for reorder
#define LSTR 136   // LDS row stride in shorts (mult of 8 -> 16B-aligned rows)

typedef short short8 __attribute__((ext_vector_type(8)));
typedef float floatx4 __attribute__((ext_vector_type(4)));

__device__ __forceinline__ unsigned short f2b(float f) {
    union { float f; unsigned u; } v; v.f = f;
    unsigned r = v.u + 0x7FFFu + ((v.u >> 16) & 1u);   // RNE
    return (unsigned short)(r >> 16);
}

__device__ __forceinline__ float b2f(unsigned short b) {
    union { unsigned u; float f; } v; v.u = (unsigned)b << 16;
    return v.f;
}

// ---------------------------------------------------------------------------
// prep: convert x/W1/W2 -> bf16 + histogram targets (hist pre-zeroed)
// ---------------------------------------------------------------------------
__global__ __launch_bounds__(256) void prep_kernel(
    const float* __restrict__ x, unsigned short* __restrict__ xB, long n4,
    const float* __restrict__ W1, const float* __restrict__ W2,
    unsigned short* __restrict__ W1B, unsigned short* __restrict__ W2B,
    const int* __restrict__ eidx, int* __restrict__ hist, int E)
{
    int tid = blockIdx.x * 256 + threadIdx.x;
    int stride = gridDim.x * 256;
    for (long i = tid; i < n4; i += stride) {
        float4 v = ((const float4*)x)[i];
        ushort4 o;
        o.x = f2b(v.x); o.y = f2b(v.y); o.z = f2b(v.z); o.w = f2b(v.w);
        ((ushort4*)xB)[i] = o;
    }
    for (int i = tid; i < HDIM * HDIM; i += stride) {
        W1B[i] = f2b(W1[i]);
        W2B[i] = f2b(W2[i]);
    }
    for (int e = tid; e < E; e += stride) {
        atomicAdd(&hist[eidx[E + e]], 1);
    }
}

// level-1 scan; block 0 also zeroes the BN stats (runs well before mega)
__global__ __launch_bounds__(256) void block_scan_kernel(
    const int* __restrict__ hist, int* __restrict__ offsets,
    int* __restrict__ blockSums, float* __restrict__ statSum, int N)
{
    __shared__ int ts[256];
    int b = blockIdx.x, t = threadIdx.x;
    if (b == 0 && t < 2 * HDIM) statSum[t] = 0.f;
    int base = b * SCAN_BINS + t * 4;
    int4 h = make_int4(0, 0, 0, 0);
    if (base + 3 < N) {
        h = *(const int4*)(hist + base);
    } else {
        if (base + 0 < N) h.x = hist[base + 0];
        if (base + 1 < N) h.y = hist[base + 1];
        if (base + 2 < N) h.z = hist[base + 2];
    }
    int s = h.x + h.y + h.z + h.w;
    ts[t] = s;
    __syncthreads();
    for (int off = 1; off < 256; off <<= 1) {
        int v = ts[t];
        int add = (t >= off) ? ts[t - off] : 0;
        __syncthreads();
        ts[t] = v + add;
        __syncthreads();
    }
    int excl = ts[t] - s;
    int4 o;
    o.x = excl;
    o.y = o.x + h.x;
    o.z = o.y + h.y;
    o.w = o.z + h.z;
    if (base + 3 < N) {
        *(int4*)(offsets + base) = o;
    } else {
        if (base + 0 < N) offsets[base + 0] = o.x;
        if (base + 1 < N) offsets[base + 1] = o.y;
        if (base + 2 < N) offsets[base + 2] = o.z;
    }
    if (t == 255) blockSums[b] = ts[255];
}

__global__ __launch_bounds__(256) void scan_finalize_kernel(
    const int* __restrict__ blockSums, int* __restrict__ offsets,
    int* __restrict__ cursor, int N, int NB)
{
    __shared__ int ts[256];
    int b = blockIdx.x, t = threadIdx.x;
    ts[t] = (t < NB) ? blockSums[t] : 0;
    __syncthreads();
    for (int off = 1; off < 256; off <<= 1) {
        int v = ts[t];
        int add = (t >= off) ? ts[t - off] : 0;
        __syncthreads();
        ts[t] = v + add;
        __syncthreads();
    }
    int prefix = (b == 0) ? 0 : ts[b - 1];
    if (b == 0 && t == 0) offsets[N] = ts[NB - 1];
    int base = b * SCAN_BINS + t * 4;
    if (base + 3 < N) {
        int4 o = *(int4*)(offsets + base);
        o.x += prefix; o.y += prefix; o.z += prefix; o.w += prefix;
        *(int4*)(offsets + base) = o;
        *(int4*)(cursor + base) = o;
    } else {
        for (int j = 0; j < 4; j++) {
            int i = base + j;
            if (i < N) {
                int v = offsets[i] + prefix;
                offsets[i] = v;
                cursor[i] = v;
            }
        }
    }
}

// XCD-partitioned reorder (blockIdx%8 ~ XCD round-robin; perf heuristic only)
__global__ __launch_bounds__(256) void reorder_kernel(
    const int* __restrict__ eidx, int* __restrict__ cursor,
    int* __restrict__ srcSorted, int E, int partSize)
{
    int part = blockIdx.x & (NPART - 1);
    int bi = blockIdx.x >> 3;
    int nb = gridDim.x >> 3;
    int lo = part * partSize;
    int hi = lo + partSize;
    int stride = nb * 256;
    for (int e = bi * 256 + threadIdx.x; e < E; e += stride) {
        int t = eidx[E + e];
        if (t >= lo && t < hi) {
            int pos = atomicAdd(&cursor[t], 1);
            srcSorted[pos] = eidx[e];
        }
    }
}

// ---------------------------------------------------------------------------
// mega_kernel: 32 rows/block (1250 blocks, 5000 waves -> ~19.5 waves/CU).
//   A: aggregate, 32 lanes/row with 2-way edge split + shfl combine -> sAgg
//   B: GEMM1: wave w does rowgrp (w&1, 16 rows) x colhalf (w>>1, 64 cols),
//      relu+b1 -> sH
//   C: GEMM2 same split + b2 -> out (fp32, pre-BN) + BN stats to global
// LDS: 2 * 32*LSTR*2B + 1KB ~= 18.4 KB
// ---------------------------------------------------------------------------
__global__ __launch_bounds__(256, 6) void mega_kernel(
    const float* __restrict__ x, const unsigned short* __restrict__ xB,
    const int* __restrict__ offsets, const int* __restrict__ srcSorted,
    const float* __restrict__ eps,
    const unsigned short* __restrict__ W1B, const float* __restrict__ b1,
    const unsigned short* __restrict__ W2B, const float* __restrict__ b2,
    float* __restrict__ out, float* __restrict__ statSum,
    float* __restrict__ statSqs, int N)
{
    __shared__ unsigned short sAgg[32 * LSTR];
    __shared__ unsigned short sH[32 * LSTR];
    __shared__ float sSum[HDIM];
    __shared__ float sSqs[HDIM];

    int tid = threadIdx.x;
    int rb = blockIdx.x * 32;
    if (tid < HDIM) { sSum[tid] = 0.f; sSqs[tid] = 0.f; }

    // ---- A: aggregate 32 rows; 32 lanes/row, halves split edges 2-way ----
    float coef = 1.0f + eps[0];
    int lane32 = tid & 31;
    int colgrp = lane32 & 15;
    int half = lane32 >> 4;
    int rp = tid >> 5;              // 8 rows per pass
    int col = colgrp * 8;
    for (int g = 0; g < 4; g++) {
        int r = g * 8 + rp;
        int row = rb + r;
        float acc[8] = {0.f, 0.f, 0.f, 0.f, 0.f, 0.f, 0.f, 0.f};
        if (row < N) {
            int beg = offsets[row], end = offsets[row + 1];
            int e = beg + half;
            for (; e + 6 < end; e += 8) {
                int s0 = srcSorted[e];
                int s1 = srcSorted[e + 2];
                int s2 = srcSorted[e + 4];
                int s3 = srcSorted[e + 6];
                short8 u0 = *(const short8*)(xB + (size_t)s0 * HDIM + col);
                short8 u1 = *(const short8*)(xB + (size_t)s1 * HDIM + col);
                short8 u2 = *(const short8*)(xB + (size_t)s2 * HDIM + col);
                short8 u3 = *(const short8*)(xB + (size_t)s3 * HDIM + col);
                #pragma unroll
                for (int j = 0; j < 8; j++)
                    acc[j] += (b2f((unsigned short)u0[j]) + b2f((unsigned short)u1[j]))
                            + (b2f((unsigned short)u2[j]) + b2f((unsigned short)u3[j]));
            }
            for (; e < end; e += 2) {
                int s = srcSorted[e];
                short8 u = *(const short8*)(xB + (size_t)s * HDIM + col);
                #pragma unroll
                for (int j = 0; j < 8; j++)
                    acc[j] += b2f((unsigned short)u[j]);
            }
            if (half == 0) {
                float4 xv0 = *(const float4*)(x + (size_t)row * HDIM + col);
                float4 xv1 = *(const float4*)(x + (size_t)row * HDIM + col + 4);
                acc[0] += coef * xv0.x; acc[1] += coef * xv0.y;
                acc[2] += coef * xv0.z; acc[3] += coef * xv0.w;
                acc[4] += coef * xv1.x; acc[5] += coef * xv1.y;
                acc[6] += coef * xv1.z; acc[7] += coef * xv1.w;
            }
        }
        // combine the two edge-halves (lane ^ 16 within the 32-lane row group)
        #pragma unroll
        for (int j = 0; j < 8; j++) acc[j] += __shfl_xor(acc[j], 16, 64);
        if (half == 0) {
            short8 o;
            #pragma unroll
            for (int j = 0; j < 8; j++) o[j] = (short)f2b(acc[j]);
            *(short8*)(sAgg + r * LSTR + col) = o;
        }
    }
    __syncthreads();

    // ---- B: GEMM1; wave w: rowgrp = w&1 (16 rows), colhalf = w>>1 (64 cols) ----
    int w = tid >> 6;
    int l = tid & 63;
    int m = l & 15, quad = l >> 4;
    int rowgrp = w & 1;
    int colhalf = w >> 1;
    const unsigned short* aSrc = sAgg + rowgrp * 16 * LSTR;
    unsigned short* hDst = sH + rowgrp * 16 * LSTR;

    floatx4 acc1[4];
    #pragma unroll
    for (int t = 0; t < 4; t++) acc1[t] = (floatx4){0.f, 0.f, 0.f, 0.f};
    #pragma unroll
    for (int kk = 0; kk < 4; kk++) {
        int k0 = kk * 32 + quad * 8;
        short8 a = *(const short8*)(aSrc + m * LSTR + k0);
        #pragma unroll
        for (int t = 0; t < 4; t++) {
            int bcol = colhalf * 64 + t * 16 + m;
            short8 bfr = *(const short8*)(W1B + (size_t)bcol * HDIM + k0);
            acc1[t] = __builtin_amdgcn_mfma_f32_16x16x32_bf16(a, bfr, acc1[t], 0, 0, 0);
        }
    }
    #pragma unroll
    for (int t = 0; t < 4; t++) {
        int colc = colhalf * 64 + t * 16 + m;
        float bs = b1[colc];
        #pragma unroll
        for (int r = 0; r < 4; r++) {
            float v = fmaxf(acc1[t][r] + bs, 0.f);
            hDst[(quad * 4 + r) * LSTR + colc] = f2b(v);
        }
    }
    __syncthreads();

    // ---- C: GEMM2 + b2 -> out (pre-BN), BN stats ----
    const unsigned short* hSrc = sH + rowgrp * 16 * LSTR;
    floatx4 acc2[4];
    #pragma unroll
    for (int t = 0; t < 4; t++) acc2[t] = (floatx4){0.f, 0.f, 0.f, 0.f};
    #pragma unroll
    for (int kk = 0; kk < 4; kk++) {
        int k0 = kk * 32 + quad * 8;
        short8 a = *(const short8*)(hSrc + m * LSTR + k0);
        #pragma unroll
        for (int t = 0; t < 4; t++) {
            int bcol = colhalf * 64 + t * 16 + m;
            short8 bfr = *(const short8*)(W2B + (size_t)bcol * HDIM + k0);
            acc2[t] = __builtin_amdgcn_mfma_f32_16x16x32_bf16(a, bfr, acc2[t], 0, 0, 0);
        }
    }
    int row0 = rb + rowgrp * 16 + quad * 4;
    #pragma unroll
    for (int t = 0; t < 4; t++) {
        int colc = colhalf * 64 + t * 16 + m;
        float bs = b2[colc];
        float cs = 0.f, cq = 0.f;
        #pragma unroll
        for (int r = 0; r < 4; r++) {
            int row = row0 + r;
            if (row < N) {
                float v = acc2[t][r] + bs;
                out[(size_t)row * HDIM + colc] = v;
                cs += v; cq += v * v;
            }
        }
        cs += __shfl_xor(cs, 16, 64);
        cs += __shfl_xor(cs, 32, 64);
        cq += __shfl_xor(cq, 16, 64);
        cq += __shfl_xor(cq, 32, 64);
        if (quad == 0) {
            atomicAdd(&sSum[colc], cs);
            atomicAdd(&sSqs[colc], cq);
        }
    }
    __syncthreads();
    if (tid < HDIM) {
        atomicAdd(&statSum[tid], sSum[tid]);
        atomicAdd(&statSqs[tid], sSqs[tid]);
    }
}

// ---------------------------------------------------------------------------
// BN apply (prep fused): per-block scale/shift in LDS, then float4 in-place
// ---------------------------------------------------------------------------
__global__ __launch_bounds__(256) void bn_apply_kernel(
    float* __restrict__ out, const float* __restrict__ statSum,
    const float* __restrict__ statSqs, const float* __restrict__ gamma,
    const float* __restrict__ beta, int N, long n4)
{
    __shared__ float sSc[HDIM];
    __shared__ float sSh[HDIM];
    int t = threadIdx.x;
    if (t < HDIM) {
        float invN = 1.0f / (float)N;
        float mean = statSum[t] * invN;
        float var = statSqs[t] * invN - mean * mean;
        float sc = gamma[t] * rsqrtf(var + BN_EPS);
        sSc[t] = sc;
        sSh[t] = beta[t] - mean * sc;
    }
    __syncthreads();
    long stride = (long)gridDim.x * 256;
    for (long i = (long)blockIdx.x * 256 + t; i < n4; i += stride) {
        int cg = (int)(i & 31) * 4;
        float4 v = ((float4*)out)[i];
        v.x = fmaxf(v.x * sSc[cg + 0] + sSh[cg + 0], 0.f);
        v.y = fmaxf(v.y * sSc[cg + 1] + sSh[cg + 1], 0.f);
        v.z = fmaxf(v.z * sSc[cg + 2] + sSh[cg + 2], 0.f);
        v.w = fmaxf(v.w * sSc[cg + 3] + sSh[cg + 3], 0.f);
        ((float4*)out)[i] = v;
    }
}

extern "C" void kernel_launch(void* const* d_in, const int* in_sizes, int n_in,
                              void* d_out, int out_size, void* d_ws, size_t ws_size,
                              hipStream_t stream) {
    const float* x     = (const float*)d_in[0];
    const int*   eidx  = (const int*)d_in[1];
    const float* eps   = (const float*)d_in[2];
    const float* W1    = (const float*)d_in[3];
    const float* b1    = (const float*)d_in[4];
    const float* W2    = (const float*)d_in[5];
    const float* b2    = (const float*)d_in[6];
    const float* gamma = (const float*)d_in[7];
    const float* beta  = (const float*)d_in[8];
    float* out = (float*)d_out;

    int N = in_sizes[0] / HDIM;
    int E = in_sizes[1] / 2;
    size_t NH = (size_t)N * HDIM;
    int NB = (N + SCAN_BINS - 1) / SCAN_BINS;
    int NpadOff = (N + 1 + 3) & ~3;
    int partSize = (N + NPART - 1) / NPART;
    long n4 = (long)NH / 4;

    unsigned short* xB   = (unsigned short*)d_ws;   // NH
    unsigned short* W1B  = xB + NH;                 // H*H
    unsigned short* W2B  = W1B + HDIM * HDIM;       // H*H
    float* statSum = (float*)(W2B + HDIM * HDIM);   // H
    float* statSqs = statSum + HDIM;                // H
    int*   hist    = (int*)(statSqs + HDIM);        // N
    int*   offsets = hist + N;                      // NpadOff
    int*   cursor  = offsets + NpadOff;             // N
    int*   srcSorted = cursor + N;                  // E
    int*   blockSums = srcSorted + E;               // NB

    // 1. zero hist
    hipMemsetAsync(hist, 0, (size_t)N * sizeof(int), stream);
    // 2. convert + histogram
    prep_kernel<<<1280, 256, 0, stream>>>(x, xB, n4, W1, W2, W1B, W2B, eidx, hist, E);
    // 3. level-1 scan (+ zero BN stats in block 0)
    block_scan_kernel<<<NB, 256, 0, stream>>>(hist, offsets, blockSums, statSum, N);
    // 4. level-2 finalize
    scan_finalize_kernel<<<NB, 256, 0, stream>>>(blockSums, offsets, cursor, N, NB);
    // 5. XCD-partitioned counting-sort reorder
    reorder_kernel<<<2048, 256, 0, stream>>>(eidx, cursor, srcSorted, E, partSize);
    // 6. aggregate + GEMM1 + GEMM2 + BN stats (32 rows/block)
    int gblocks = (N + 31) / 32;
    mega_kernel<<<gblocks, 256, 0, stream>>>(
        x, xB, offsets, srcSorted, eps, W1B, b1, W2B, b2,
        out, statSum, statSqs, N);
    // 7. BN scale/shift + apply + final ReLU
    bn_apply_kernel<<<2048, 256, 0, stream>>>(
        out, statSum, statSqs, gamma, beta, N, n4);
}

// Round 12
// 201.407 us; speedup vs baseline: 1.1156x; 1.1156x over previous
//
#include <hip/hip_runtime.h>

#define HDIM 128
#define BN_EPS 1e-5f
#define SCAN_BINS 1024
#define NPART 8    // XCD count: target-range partitions for reorder
#define LSTR 136   // LDS row stride in shorts (mult of 8 -> 16B-aligned rows)

typedef short short8 __attribute__((ext_vector_type(8)));
typedef float floatx4 __attribute__((ext_vector_type(4)));

__device__ __forceinline__ unsigned short f2b(float f) {
    union { float f; unsigned u; } v; v.f = f;
    unsigned r = v.u + 0x7FFFu + ((v.u >> 16) & 1u);   // RNE
    return (unsigned short)(r >> 16);
}

__device__ __forceinline__ float b2f(unsigned short b) {
    union { unsigned u; float f; } v; v.u = (unsigned)b << 16;
    return v.f;
}

// ---------------------------------------------------------------------------
// prep: convert x/W1/W2 -> bf16 + histogram targets; the atomicAdd return
// value IS the edge's rank within its target bucket -> store it (free).
// ---------------------------------------------------------------------------
__global__ __launch_bounds__(256) void prep_kernel(
    const float* __restrict__ x, unsigned short* __restrict__ xB, long n4,
    const float* __restrict__ W1, const float* __restrict__ W2,
    unsigned short* __restrict__ W1B, unsigned short* __restrict__ W2B,
    const int* __restrict__ eidx, int* __restrict__ hist,
    int* __restrict__ rank, int E)
{
    int tid = blockIdx.x * 256 + threadIdx.x;
    int stride = gridDim.x * 256;
    for (long i = tid; i < n4; i += stride) {
        float4 v = ((const float4*)x)[i];
        ushort4 o;
        o.x = f2b(v.x); o.y = f2b(v.y); o.z = f2b(v.z); o.w = f2b(v.w);
        ((ushort4*)xB)[i] = o;
    }
    for (int i = tid; i < HDIM * HDIM; i += stride) {
        W1B[i] = f2b(W1[i]);
        W2B[i] = f2b(W2[i]);
    }
    for (int e = tid; e < E; e += stride) {
        rank[e] = atomicAdd(&hist[eidx[E + e]], 1);
    }
}

// level-1 scan; block 0 also zeroes the BN stats (runs well before mega)
__global__ __launch_bounds__(256) void block_scan_kernel(
    const int* __restrict__ hist, int* __restrict__ offsets,
    int* __restrict__ blockSums, float* __restrict__ statSum, int N)
{
    __shared__ int ts[256];
    int b = blockIdx.x, t = threadIdx.x;
    if (b == 0 && t < 2 * HDIM) statSum[t] = 0.f;
    int base = b * SCAN_BINS + t * 4;
    int4 h = make_int4(0, 0, 0, 0);
    if (base + 3 < N) {
        h = *(const int4*)(hist + base);
    } else {
        if (base + 0 < N) h.x = hist[base + 0];
        if (base + 1 < N) h.y = hist[base + 1];
        if (base + 2 < N) h.z = hist[base + 2];
    }
    int s = h.x + h.y + h.z + h.w;
    ts[t] = s;
    __syncthreads();
    for (int off = 1; off < 256; off <<= 1) {
        int v = ts[t];
        int add = (t >= off) ? ts[t - off] : 0;
        __syncthreads();
        ts[t] = v + add;
        __syncthreads();
    }
    int excl = ts[t] - s;
    int4 o;
    o.x = excl;
    o.y = o.x + h.x;
    o.z = o.y + h.y;
    o.w = o.z + h.z;
    if (base + 3 < N) {
        *(int4*)(offsets + base) = o;
    } else {
        if (base + 0 < N) offsets[base + 0] = o.x;
        if (base + 1 < N) offsets[base + 1] = o.y;
        if (base + 2 < N) offsets[base + 2] = o.z;
    }
    if (t == 255) blockSums[b] = ts[255];
}

__global__ __launch_bounds__(256) void scan_finalize_kernel(
    const int* __restrict__ blockSums, int* __restrict__ offsets, int N, int NB)
{
    __shared__ int ts[256];
    int b = blockIdx.x, t = threadIdx.x;
    ts[t] = (t < NB) ? blockSums[t] : 0;
    __syncthreads();
    for (int off = 1; off < 256; off <<= 1) {
        int v = ts[t];
        int add = (t >= off) ? ts[t - off] : 0;
        __syncthreads();
        ts[t] = v + add;
        __syncthreads();
    }
    int prefix = (b == 0) ? 0 : ts[b - 1];
    if (b == 0 && t == 0) offsets[N] = ts[NB - 1];
    int base = b * SCAN_BINS + t * 4;
    if (base + 3 < N) {
        int4 o = *(int4*)(offsets + base);
        o.x += prefix; o.y += prefix; o.z += prefix; o.w += prefix;
        *(int4*)(offsets + base) = o;
    } else {
        for (int j = 0; j < 4; j++) {
            int i = base + j;
            if (i < N) offsets[i] += prefix;
        }
    }
}

// Atomic-free reorder: position = offsets[tgt] + rank[e]. XCD-partitioned
// (blockIdx%8 ~ XCD round-robin; perf heuristic only) for write locality.
__global__ __launch_bounds__(256) void reorder_kernel(
    const int* __restrict__ eidx, const int* __restrict__ offsets,
    const int* __restrict__ rank, int* __restrict__ srcSorted,
    int E, int partSize)
{
    int part = blockIdx.x & (NPART - 1);
    int bi = blockIdx.x >> 3;
    int nb = gridDim.x >> 3;
    int lo = part * partSize;
    int hi = lo + partSize;
    int stride = nb * 256;
    for (int e = bi * 256 + threadIdx.x; e < E; e += stride) {
        int t = eidx[E + e];
        if (t >= lo && t < hi) {
            srcSorted[offsets[t] + rank[e]] = eidx[e];
        }
    }
}

// ---------------------------------------------------------------------------
// mega_kernel (round-10 shape, 64 rows/block, 8-way gather ILP):
//   A: aggregate 64 rows -> LDS tile (8 loads in flight per lane)
//   B: GEMM1; relu+b1 written IN PLACE over the wave's own 16 rows
//   C: GEMM2 + b2 -> out (fp32, pre-BN) + BN stats to global
// ---------------------------------------------------------------------------
__global__ __launch_bounds__(256, 4) void mega_kernel(
    const float* __restrict__ x, const unsigned short* __restrict__ xB,
    const int* __restrict__ offsets, const int* __restrict__ srcSorted,
    const float* __restrict__ eps,
    const unsigned short* __restrict__ W1B, const float* __restrict__ b1,
    const unsigned short* __restrict__ W2B, const float* __restrict__ b2,
    float* __restrict__ out, float* __restrict__ statSum,
    float* __restrict__ statSqs, int N)
{
    __shared__ unsigned short sT[64 * LSTR];   // agg tile, then h1 in place
    __shared__ float sSum[HDIM];
    __shared__ float sSqs[HDIM];

    int tid = threadIdx.x;
    int rb = blockIdx.x * 64;
    if (tid < HDIM) { sSum[tid] = 0.f; sSqs[tid] = 0.f; }

    // ---- A: aggregate 64 rows into sT (8-way unrolled gather) ----
    float coef = 1.0f + eps[0];
    int tx = tid & 15, ty = tid >> 4;
    int col = tx * 8;
    for (int g = 0; g < 4; g++) {
        int r = g * 16 + ty;
        int row = rb + r;
        float acc[8] = {0.f, 0.f, 0.f, 0.f, 0.f, 0.f, 0.f, 0.f};
        if (row < N) {
            float4 xv0 = *(const float4*)(x + (size_t)row * HDIM + col);
            float4 xv1 = *(const float4*)(x + (size_t)row * HDIM + col + 4);
            acc[0] = coef * xv0.x; acc[1] = coef * xv0.y;
            acc[2] = coef * xv0.z; acc[3] = coef * xv0.w;
            acc[4] = coef * xv1.x; acc[5] = coef * xv1.y;
            acc[6] = coef * xv1.z; acc[7] = coef * xv1.w;
            int beg = offsets[row], end = offsets[row + 1];
            int e = beg;
            for (; e + 7 < end; e += 8) {
                short8 u[8];
                #pragma unroll
                for (int q = 0; q < 8; q++) {
                    int s = srcSorted[e + q];
                    u[q] = *(const short8*)(xB + (size_t)s * HDIM + col);
                }
                #pragma unroll
                for (int q = 0; q < 8; q++)
                    #pragma unroll
                    for (int j = 0; j < 8; j++)
                        acc[j] += b2f((unsigned short)u[q][j]);
            }
            for (; e < end; e++) {
                int s = srcSorted[e];
                short8 u = *(const short8*)(xB + (size_t)s * HDIM + col);
                #pragma unroll
                for (int j = 0; j < 8; j++)
                    acc[j] += b2f((unsigned short)u[j]);
            }
        }
        short8 o;
        #pragma unroll
        for (int j = 0; j < 8; j++) o[j] = (short)f2b(acc[j]);
        *(short8*)(sT + r * LSTR + col) = o;
    }
    __syncthreads();

    // ---- B: GEMM1 from LDS; h1 written in place over the wave's rows ----
    int w = tid >> 6;
    int l = tid & 63;
    int m = l & 15, quad = l >> 4;
    unsigned short* myT = sT + w * 16 * LSTR;

    floatx4 acc1[8];
    #pragma unroll
    for (int t = 0; t < 8; t++) acc1[t] = (floatx4){0.f, 0.f, 0.f, 0.f};
    #pragma unroll
    for (int kk = 0; kk < 4; kk++) {
        int k0 = kk * 32 + quad * 8;
        short8 a = *(const short8*)(myT + m * LSTR + k0);
        #pragma unroll
        for (int t = 0; t < 8; t++) {
            short8 bfr = *(const short8*)(W1B + (size_t)(t * 16 + m) * HDIM + k0);
            acc1[t] = __builtin_amdgcn_mfma_f32_16x16x32_bf16(a, bfr, acc1[t], 0, 0, 0);
        }
    }
    #pragma unroll
    for (int t = 0; t < 8; t++) {
        int colc = t * 16 + m;
        float bs = b1[colc];
        #pragma unroll
        for (int r = 0; r < 4; r++) {
            float v = fmaxf(acc1[t][r] + bs, 0.f);
            myT[(quad * 4 + r) * LSTR + colc] = f2b(v);
        }
    }
    // no barrier needed: wave w only touches its own 16 rows

    // ---- C: GEMM2 from LDS + b2 -> out (pre-BN), BN stats ----
    floatx4 acc2[8];
    #pragma unroll
    for (int t = 0; t < 8; t++) acc2[t] = (floatx4){0.f, 0.f, 0.f, 0.f};
    #pragma unroll
    for (int kk = 0; kk < 4; kk++) {
        int k0 = kk * 32 + quad * 8;
        short8 a = *(const short8*)(myT + m * LSTR + k0);
        #pragma unroll
        for (int t = 0; t < 8; t++) {
            short8 bfr = *(const short8*)(W2B + (size_t)(t * 16 + m) * HDIM + k0);
            acc2[t] = __builtin_amdgcn_mfma_f32_16x16x32_bf16(a, bfr, acc2[t], 0, 0, 0);
        }
    }
    int row0 = rb + w * 16 + quad * 4;
    #pragma unroll
    for (int t = 0; t < 8; t++) {
        int colc = t * 16 + m;
        float bs = b2[colc];
        float cs = 0.f, cq = 0.f;
        #pragma unroll
        for (int r = 0; r < 4; r++) {
            int row = row0 + r;
            if (row < N) {
                float v = acc2[t][r] + bs;
                out[(size_t)row * HDIM + colc] = v;
                cs += v; cq += v * v;
            }
        }
        cs += __shfl_xor(cs, 16, 64);
        cs += __shfl_xor(cs, 32, 64);
        cq += __shfl_xor(cq, 16, 64);
        cq += __shfl_xor(cq, 32, 64);
        if (quad == 0) {
            atomicAdd(&sSum[colc], cs);
            atomicAdd(&sSqs[colc], cq);
        }
    }
    __syncthreads();
    if (tid < HDIM) {
        atomicAdd(&statSum[tid], sSum[tid]);
        atomicAdd(&statSqs[tid], sSqs[tid]);
    }
}

// ---------------------------------------------------------------------------
// BN apply (prep fused): per-block scale/shift in LDS, then float4 in-place
// ---------------------------------------------------------------------------
__global__ __launch_bounds__(256) void bn_apply_kernel(
    float* __restrict__ out, const float* __restrict__ statSum,
    const float* __restrict__ statSqs, const float* __restrict__ gamma,
    const float* __restrict__ beta, int N, long n4)
{
    __shared__ float sSc[HDIM];
    __shared__ float sSh[HDIM];
    int t = threadIdx.x;
    if (t < HDIM) {
        float invN = 1.0f / (float)N;
        float mean = statSum[t] * invN;
        float var = statSqs[t] * invN - mean * mean;
        float sc = gamma[t] * rsqrtf(var + BN_EPS);
        sSc[t] = sc;
        sSh[t] = beta[t] - mean * sc;
    }
    __syncthreads();
    long stride = (long)gridDim.x * 256;
    for (long i = (long)blockIdx.x * 256 + t; i < n4; i += stride) {
        int cg = (int)(i & 31) * 4;
        float4 v = ((float4*)out)[i];
        v.x = fmaxf(v.x * sSc[cg + 0] + sSh[cg + 0], 0.f);
        v.y = fmaxf(v.y * sSc[cg + 1] + sSh[cg + 1], 0.f);
        v.z = fmaxf(v.z * sSc[cg + 2] + sSh[cg + 2], 0.f);
        v.w = fmaxf(v.w * sSc[cg + 3] + sSh[cg + 3], 0.f);
        ((float4*)out)[i] = v;
    }
}

extern "C" void kernel_launch(void* const* d_in, const int* in_sizes, int n_in,
                              void* d_out, int out_size, void* d_ws, size_t ws_size,
                              hipStream_t stream) {
    const float* x     = (const float*)d_in[0];
    const int*   eidx  = (const int*)d_in[1];
    const float* eps   = (const float*)d_in[2];
    const float* W1    = (const float*)d_in[3];
    const float* b1    = (const float*)d_in[4];
    const float* W2    = (const float*)d_in[5];
    const float* b2    = (const float*)d_in[6];
    const float* gamma = (const float*)d_in[7];
    const float* beta  = (const float*)d_in[8];
    float* out = (float*)d_out;

    int N = in_sizes[0] / HDIM;
    int E = in_sizes[1] / 2;
    size_t NH = (size_t)N * HDIM;
    int NB = (N + SCAN_BINS - 1) / SCAN_BINS;
    int NpadOff = (N + 1 + 3) & ~3;
    int partSize = (N + NPART - 1) / NPART;
    long n4 = (long)NH / 4;

    unsigned short* xB   = (unsigned short*)d_ws;   // NH
    unsigned short* W1B  = xB + NH;                 // H*H
    unsigned short* W2B  = W1B + HDIM * HDIM;       // H*H
    float* statSum = (float*)(W2B + HDIM * HDIM);   // H
    float* statSqs = statSum + HDIM;                // H
    int*   hist    = (int*)(statSqs + HDIM);        // N
    int*   offsets = hist + N;                      // NpadOff
    int*   rank    = offsets + NpadOff;             // E
    int*   srcSorted = rank + E;                    // E
    int*   blockSums = srcSorted + E;               // NB

    // 1. zero hist
    hipMemsetAsync(hist, 0, (size_t)N * sizeof(int), stream);
    // 2. convert + histogram (rank captured from atomicAdd return)
    prep_kernel<<<1280, 256, 0, stream>>>(x, xB, n4, W1, W2, W1B, W2B, eidx, hist, rank, E);
    // 3. level-1 scan (+ zero BN stats in block 0)
    block_scan_kernel<<<NB, 256, 0, stream>>>(hist, offsets, blockSums, statSum, N);
    // 4. level-2 finalize
    scan_finalize_kernel<<<NB, 256, 0, stream>>>(blockSums, offsets, N, NB);
    // 5. atomic-free XCD-partitioned reorder
    reorder_kernel<<<2048, 256, 0, stream>>>(eidx, offsets, rank, srcSorted, E, partSize);
    // 6. aggregate + GEMM1 + GEMM2 + BN stats (64 rows/block)
    int gblocks = (N + 63) / 64;
    mega_kernel<<<gblocks, 256, 0, stream>>>(
        x, xB, offsets, srcSorted, eps, W1B, b1, W2B, b2,
        out, statSum, statSqs, N);
    // 7. BN scale/shift + apply + final ReLU
    bn_apply_kernel<<<2048, 256, 0, stream>>>(
        out, statSum, statSqs, gamma, beta, N, n4);
}